// Round 4
// baseline (202.303 us; speedup 1.0000x reference)
//
#include <hip/hip_runtime.h>

// Problem constants
#define N_NODES 100000
#define S_SAMP  2048
#define E_EDGE  131072
#define NBLK    512            // 512 blocks x 256 thr; <=4 blocks/CU capacity -> all co-resident
#define SBLK0   391            // blocks 391..398 handle the 2048 samples (no n-work there)

// Workspace float offsets
#define SPA_OFF     0
#define CNT_OFF     8                            // u32 barrier counter at W[8]
#define CS_PART_OFF 64                           // NBLK*8 = 4096
#define M2P_OFF     (CS_PART_OFF + NBLK*8)       // 4160: 8*64 = 512
#define PART_OFF    (M2P_OFF + 512)              // 4672: NBLK
#define BS_OFF      (PART_OFF + NBLK)            // 5184: 2048
#define MS_OFF      (BS_OFF + S_SAMP)            // 7232: 16384
#define ZT_OFF      (MS_OFF + S_SAMP*8)          // 23616: N*8
#define VT_OFF      (ZT_OFF + N_NODES*8)         // 823616: N*8
// end = 1,623,616 floats ~= 6.5 MB

__device__ __forceinline__ void gridbar(unsigned* cnt, unsigned target) {
    __syncthreads();
    if (threadIdx.x == 0) {
        __threadfence();   // release prior global writes (device scope)
        __hip_atomic_fetch_add(cnt, 1u, __ATOMIC_RELEASE, __HIP_MEMORY_SCOPE_AGENT);
        while (__hip_atomic_load(cnt, __ATOMIC_ACQUIRE, __HIP_MEMORY_SCOPE_AGENT) < target)
            __builtin_amdgcn_s_sleep(2);
    }
    __syncthreads();
}

__global__ __launch_bounds__(256, 4) void k_all(
    const float* __restrict__ beta, const float* __restrict__ a,
    const float* __restrict__ Zp,   const float* __restrict__ Gp,
    const int* __restrict__ sidx,   const int* __restrict__ si,
    const int* __restrict__ sj,     float* __restrict__ out,
    float* __restrict__ W)
{
    const int tid  = threadIdx.x, bid = blockIdx.x;
    const int lane = tid & 63,    wave = tid >> 6;
    unsigned* cnt = (unsigned*)W + CNT_OFF;

    __shared__ float  sred[4][64];
    __shared__ float  sflat[256];
    __shared__ float  sinv8[8];
    __shared__ float  sM2[64];
    __shared__ double sd[256];
    __shared__ int    sLast;

    const bool isSamp = (bid >= SBLK0) && (bid < SBLK0 + 8);
    float zs[8], ws8[8];     // sample-block registers, persist across barriers

    // ================= P0: zt=softmax(Zp) cols; colsum partials; sample M2raw; Bs; spa
    {
        int n = bid * 256 + tid;
        float part[8] = {0,0,0,0,0,0,0,0};
        if (n < N_NODES) {
            float zv[8]; float mx = -1e30f;
            #pragma unroll
            for (int k = 0; k < 8; ++k) {
                zv[k] = Zp[(size_t)k * N_NODES + n];
                mx = fmaxf(mx, zv[k]);
            }
            float den = 0.f;
            #pragma unroll
            for (int k = 0; k < 8; ++k) { zv[k] = __expf(zv[k] - mx); den += zv[k]; }
            float inv = 1.f / den;
            float4 g0 = *(const float4*)&Gp[(size_t)n * 8];
            float4 g1 = *(const float4*)&Gp[(size_t)n * 8 + 4];
            float g[8] = {g0.x,g0.y,g0.z,g0.w,g1.x,g1.y,g1.z,g1.w};
            float zt[8];
            #pragma unroll
            for (int k = 0; k < 8; ++k) {
                float z = zv[k] * inv;
                zt[k] = z;
                part[k] = z / (1.f + __expf(-g[k]));
            }
            *(float4*)&W[ZT_OFF + (size_t)n * 8]     = make_float4(zt[0],zt[1],zt[2],zt[3]);
            *(float4*)&W[ZT_OFF + (size_t)n * 8 + 4] = make_float4(zt[4],zt[5],zt[6],zt[7]);
        }
        #pragma unroll
        for (int k = 0; k < 8; ++k) {
            float x = part[k];
            #pragma unroll
            for (int off = 32; off; off >>= 1) x += __shfl_down(x, off, 64);
            if (lane == 0) sred[wave][k] = x;
        }
        __syncthreads();
        if (tid < 8)
            W[CS_PART_OFF + bid * 8 + tid] =
                sred[0][tid] + sred[1][tid] + sred[2][tid] + sred[3][tid];
        if (bid == NBLK - 1 && tid == 0) {
            float av = a[0];
            W[SPA_OFF] = fmaxf(av, 0.f) + log1pf(__expf(-fabsf(av)));  // softplus(a)
        }
        if (isSamp) {
            int s = (bid - SBLK0) * 256 + tid;   // exactly S_SAMP threads
            int idx = sidx[s];
            float zv[8]; float mx = -1e30f;
            #pragma unroll
            for (int k = 0; k < 8; ++k) {
                zv[k] = Zp[(size_t)k * N_NODES + idx];
                mx = fmaxf(mx, zv[k]);
            }
            float den = 0.f;
            #pragma unroll
            for (int k = 0; k < 8; ++k) { zv[k] = __expf(zv[k] - mx); den += zv[k]; }
            float inv = 1.f / den;
            float4 g0 = *(const float4*)&Gp[(size_t)idx * 8];
            float4 g1 = *(const float4*)&Gp[(size_t)idx * 8 + 4];
            float g[8] = {g0.x,g0.y,g0.z,g0.w,g1.x,g1.y,g1.z,g1.w};
            #pragma unroll
            for (int k = 0; k < 8; ++k) {
                zs[k]  = zv[k] * inv;
                ws8[k] = zs[k] / (1.f + __expf(-g[k]));
            }
            W[BS_OFF + s] = beta[idx];
            __syncthreads();                     // guard sred reuse
            #pragma unroll
            for (int k = 0; k < 8; ++k) {
                #pragma unroll
                for (int j = 0; j < 8; ++j) {
                    float x = zs[k] * ws8[j];
                    #pragma unroll
                    for (int off = 32; off; off >>= 1) x += __shfl_down(x, off, 64);
                    if (lane == 0) sred[wave][k * 8 + j] = x;
                }
            }
            __syncthreads();
            if (tid < 64)
                W[M2P_OFF + (bid - SBLK0) * 64 + tid] =
                    sred[0][tid] + sred[1][tid] + sred[2][tid] + sred[3][tid];
        }
    }
    gridbar(cnt, NBLK);

    // ================= P1: every block re-reduces partials -> M2; vt; Ms (from regs)
    {
        int k = tid & 7, g = tid >> 3;
        float s = 0.f;
        for (int b = g; b < NBLK; b += 32) s += W[CS_PART_OFF + b * 8 + k];
        sflat[tid] = s;
    }
    __syncthreads();
    if (tid < 8) {
        float s = 0.f;
        #pragma unroll
        for (int g = 0; g < 32; ++g) s += sflat[g * 8 + tid];
        sinv8[tid] = 1.f / s;
    }
    __syncthreads();
    if (tid < 64) {
        float m = 0.f;
        #pragma unroll
        for (int b = 0; b < 8; ++b) m += W[M2P_OFF + b * 64 + tid];
        sM2[tid] = m * sinv8[tid & 7];           // M2[k][j] = raw[k][j]/colsum[j]
    }
    __syncthreads();
    {
        int n = bid * 256 + tid;
        if (n < N_NODES) {
            float4 z0 = *(const float4*)&W[ZT_OFF + (size_t)n * 8];
            float4 z1 = *(const float4*)&W[ZT_OFF + (size_t)n * 8 + 4];
            float z[8] = {z0.x,z0.y,z0.z,z0.w,z1.x,z1.y,z1.z,z1.w};
            float v[8];
            #pragma unroll
            for (int k = 0; k < 8; ++k) {
                float acc = 0.f;
                #pragma unroll
                for (int j = 0; j < 8; ++j) acc += sM2[k * 8 + j] * z[j];
                v[k] = acc;
            }
            *(float4*)&W[VT_OFF + (size_t)n * 8]     = make_float4(v[0],v[1],v[2],v[3]);
            *(float4*)&W[VT_OFF + (size_t)n * 8 + 4] = make_float4(v[4],v[5],v[6],v[7]);
        }
        if (isSamp) {                            // Ms from registers, no gathers
            int s = (bid - SBLK0) * 256 + tid;
            float v[8];
            #pragma unroll
            for (int k = 0; k < 8; ++k) {
                float acc = 0.f;
                #pragma unroll
                for (int j = 0; j < 8; ++j) acc += sM2[k * 8 + j] * zs[j];
                v[k] = acc;
            }
            *(float4*)&W[MS_OFF + (size_t)s * 8]     = make_float4(v[0],v[1],v[2],v[3]);
            *(float4*)&W[MS_OFF + (size_t)s * 8 + 4] = make_float4(v[4],v[5],v[6],v[7]);
        }
    }
    gridbar(cnt, 2 * NBLK);

    // ================= P2: pair rows (4/block, t-outer) + sparse (1 edge/thread)
    {
        const float spa = W[SPA_OFF];
        const float* Ms = W + MS_OFF;
        const float* Bs = W + BS_OFF;
        float4 r0[4], r1[4]; float bsv[4]; int srow0 = bid * 4;
        #pragma unroll
        for (int r = 0; r < 4; ++r) {
            r0[r] = *(const float4*)&Ms[(size_t)(srow0 + r) * 8];
            r1[r] = *(const float4*)&Ms[(size_t)(srow0 + r) * 8 + 4];
            bsv[r] = Bs[srow0 + r];
        }
        float accp = 0.f;
        #pragma unroll
        for (int m = 0; m < 8; ++m) {
            int t = tid + 256 * m;
            float4 a0 = *(const float4*)&Ms[(size_t)t * 8];
            float4 a1 = *(const float4*)&Ms[(size_t)t * 8 + 4];
            float bt = Bs[t];
            #pragma unroll
            for (int r = 0; r < 4; ++r) {
                float d, ss;
                d = r0[r].x - a0.x + 1e-6f; ss  = d * d;
                d = r0[r].y - a0.y + 1e-6f; ss += d * d;
                d = r0[r].z - a0.z + 1e-6f; ss += d * d;
                d = r0[r].w - a0.w + 1e-6f; ss += d * d;
                d = r1[r].x - a1.x + 1e-6f; ss += d * d;
                d = r1[r].y - a1.y + 1e-6f; ss += d * d;
                d = r1[r].z - a1.z + 1e-6f; ss += d * d;
                d = r1[r].w - a1.w + 1e-6f; ss += d * d;
                float val = __expf(bsv[r] + bt - spa * sqrtf(ss));
                if (t != srow0 + r) accp += val;
            }
        }
        float accs;
        {
            int e = bid * 256 + tid;             // NBLK*256 == E exactly
            int i = si[e], j = sj[e];
            const float* vt = W + VT_OFF;
            float4 vi0 = *(const float4*)&vt[(size_t)i * 8];
            float4 vi1 = *(const float4*)&vt[(size_t)i * 8 + 4];
            float4 vj0 = *(const float4*)&vt[(size_t)j * 8];
            float4 vj1 = *(const float4*)&vt[(size_t)j * 8 + 4];
            float d, ss;
            d = vi0.x - vj0.x + 1e-6f; ss  = d * d;
            d = vi0.y - vj0.y + 1e-6f; ss += d * d;
            d = vi0.z - vj0.z + 1e-6f; ss += d * d;
            d = vi0.w - vj0.w + 1e-6f; ss += d * d;
            d = vi1.x - vj1.x + 1e-6f; ss += d * d;
            d = vi1.y - vj1.y + 1e-6f; ss += d * d;
            d = vi1.z - vj1.z + 1e-6f; ss += d * d;
            d = vi1.w - vj1.w + 1e-6f; ss += d * d;
            accs = beta[i] + beta[j] - spa * sqrtf(ss);
        }
        float part = accs - 0.5f * 7.38905609893065f * accp;   // e^2
        #pragma unroll
        for (int off = 32; off; off >>= 1) part += __shfl_down(part, off, 64);
        if (lane == 0) sflat[wave] = part;
        __syncthreads();
        if (tid == 0)
            W[PART_OFF + bid] = sflat[0] + sflat[1] + sflat[2] + sflat[3];
    }

    // ================= P3: last-block deterministic final reduce
    if (tid == 0) {
        __threadfence();
        unsigned old = __hip_atomic_fetch_add(cnt, 1u, __ATOMIC_ACQ_REL,
                                              __HIP_MEMORY_SCOPE_AGENT);
        sLast = (old == 3u * NBLK - 1u);
    }
    __syncthreads();
    if (sLast) {
        double s = (double)W[PART_OFF + tid] + (double)W[PART_OFF + tid + 256];
        sd[tid] = s;
        __syncthreads();
        for (int k = 128; k > 0; k >>= 1) {
            if (tid < k) sd[tid] += sd[tid + k];
            __syncthreads();
        }
        if (tid == 0) out[0] = (float)sd[0];
    }
}

extern "C" void kernel_launch(void* const* d_in, const int* in_sizes, int n_in,
                              void* d_out, int out_size, void* d_ws, size_t ws_size,
                              hipStream_t stream) {
    const float* beta       = (const float*)d_in[0];
    const float* a          = (const float*)d_in[1];
    const float* Zp         = (const float*)d_in[2];
    const float* Gp         = (const float*)d_in[3];
    const int*   sample_idx = (const int*)d_in[4];
    const int*   sparse_i   = (const int*)d_in[5];
    const int*   sparse_j   = (const int*)d_in[6];
    float* out = (float*)d_out;
    float* W   = (float*)d_ws;

    // zero the barrier counter (captured node -> runs every replay)
    hipMemsetAsync((char*)d_ws + CNT_OFF * 4, 0, 4, stream);
    k_all<<<dim3(NBLK), dim3(256), 0, stream>>>(beta, a, Zp, Gp,
                                                sample_idx, sparse_i, sparse_j,
                                                out, W);
}

// Round 5
// 57.936 us; speedup vs baseline: 3.4919x; 3.4919x over previous
//
#include <hip/hip_runtime.h>

// Problem constants
#define N_NODES 100000
#define S_SAMP  2048
#define E_EDGE  131072
#define NB      391            // ceil(N/256) blocks for K1
#define PB      512            // K2 blocks: 4 pair rows each; 512*256 == E exactly

// Workspace float offsets
#define SPA_OFF     0
#define CNT_OFF     8                        // u32 arrival counter at W[8]
#define CS_PART_OFF 64                       // NB*8 = 3128
#define M2P_OFF     (CS_PART_OFF + 3200)     // 8*64 = 512
#define PART_OFF    (M2P_OFF + 512)          // PB = 512
#define BS_OFF      (PART_OFF + PB)          // 2048
#define ZS_OFF      (BS_OFF + S_SAMP)        // 2048*8 = 16384 (sample softmax cols)
#define ZT_OFF      (ZS_OFF + S_SAMP*8)      // N*8 = 800000
// end = 822,656 floats ~= 3.3 MB

// ---------------------------------------------------------------------------
// K1: zt = softmax(Zp) per column; per-block colsum partials; sample blocks
//     (bid<8) also: sample softmax -> Zs, Bs, M2raw partials; bid==NB-1: spa +
//     counter reset.
// ---------------------------------------------------------------------------
__global__ __launch_bounds__(256) void k1(const float* __restrict__ beta,
                                          const float* __restrict__ a,
                                          const float* __restrict__ Zp,
                                          const float* __restrict__ Gp,
                                          const int* __restrict__ sidx,
                                          float* __restrict__ W) {
    const int tid = threadIdx.x, bid = blockIdx.x;
    const int n = bid * 256 + tid;
    const int lane = tid & 63, wave = tid >> 6;
    __shared__ float sred[4][64];

    float part[8] = {0,0,0,0,0,0,0,0};
    if (n < N_NODES) {
        float zv[8]; float mx = -1e30f;
        #pragma unroll
        for (int k = 0; k < 8; ++k) {
            zv[k] = Zp[(size_t)k * N_NODES + n];
            mx = fmaxf(mx, zv[k]);
        }
        float den = 0.f;
        #pragma unroll
        for (int k = 0; k < 8; ++k) { zv[k] = __expf(zv[k] - mx); den += zv[k]; }
        float inv = 1.f / den;
        float4 g0 = *(const float4*)&Gp[(size_t)n * 8];
        float4 g1 = *(const float4*)&Gp[(size_t)n * 8 + 4];
        float g[8] = {g0.x,g0.y,g0.z,g0.w,g1.x,g1.y,g1.z,g1.w};
        float zt[8];
        #pragma unroll
        for (int k = 0; k < 8; ++k) {
            float z = zv[k] * inv;
            zt[k] = z;
            part[k] = z / (1.f + __expf(-g[k]));
        }
        *(float4*)&W[ZT_OFF + (size_t)n * 8]     = make_float4(zt[0],zt[1],zt[2],zt[3]);
        *(float4*)&W[ZT_OFF + (size_t)n * 8 + 4] = make_float4(zt[4],zt[5],zt[6],zt[7]);
    }
    #pragma unroll
    for (int k = 0; k < 8; ++k) {
        float x = part[k];
        #pragma unroll
        for (int off = 32; off; off >>= 1) x += __shfl_down(x, off, 64);
        if (lane == 0) sred[wave][k] = x;
    }
    __syncthreads();
    if (tid < 8)
        W[CS_PART_OFF + bid * 8 + tid] =
            sred[0][tid] + sred[1][tid] + sred[2][tid] + sred[3][tid];
    if (bid == NB - 1 && tid == 0) {
        float av = a[0];
        W[SPA_OFF] = fmaxf(av, 0.f) + log1pf(__expf(-fabsf(av)));  // softplus(a)
        ((unsigned*)W)[CNT_OFF] = 0u;                               // K2 counter
    }

    // ---- sample blocks (0..7): sample softmax -> Zs/Bs + M2raw partials ----
    if (bid < 8) {
        int s = bid * 256 + tid;            // exactly S_SAMP threads
        int idx = sidx[s];
        float zv[8]; float mx = -1e30f;
        #pragma unroll
        for (int k = 0; k < 8; ++k) {
            zv[k] = Zp[(size_t)k * N_NODES + idx];
            mx = fmaxf(mx, zv[k]);
        }
        float den = 0.f;
        #pragma unroll
        for (int k = 0; k < 8; ++k) { zv[k] = __expf(zv[k] - mx); den += zv[k]; }
        float inv = 1.f / den;
        float4 g0 = *(const float4*)&Gp[(size_t)idx * 8];
        float4 g1 = *(const float4*)&Gp[(size_t)idx * 8 + 4];
        float g[8] = {g0.x,g0.y,g0.z,g0.w,g1.x,g1.y,g1.z,g1.w};
        float z[8], w8[8];
        #pragma unroll
        for (int k = 0; k < 8; ++k) {
            z[k]  = zv[k] * inv;
            w8[k] = z[k] / (1.f + __expf(-g[k]));
        }
        *(float4*)&W[ZS_OFF + (size_t)s * 8]     = make_float4(z[0],z[1],z[2],z[3]);
        *(float4*)&W[ZS_OFF + (size_t)s * 8 + 4] = make_float4(z[4],z[5],z[6],z[7]);
        W[BS_OFF + s] = beta[idx];

        __syncthreads();                    // guard sred reuse
        #pragma unroll
        for (int k = 0; k < 8; ++k) {
            #pragma unroll
            for (int j = 0; j < 8; ++j) {
                float x = z[k] * w8[j];
                #pragma unroll
                for (int off = 32; off; off >>= 1) x += __shfl_down(x, off, 64);
                if (lane == 0) sred[wave][k * 8 + j] = x;
            }
        }
        __syncthreads();
        if (tid < 64)
            W[M2P_OFF + bid * 64 + tid] =
                sred[0][tid] + sred[1][tid] + sred[2][tid] + sred[3][tid];
    }
}

// ---------------------------------------------------------------------------
// K2: every block rebuilds M2 (LDS); pair rows 4/block with on-the-fly
//     Ms = M2 @ Zs; sparse 1 edge/thread via M2 @ (zt_i - zt_j); block
//     partial; last-block deterministic final reduce -> out.
// ---------------------------------------------------------------------------
__global__ __launch_bounds__(256, 2) void k2(const float* __restrict__ beta,
                                             const int* __restrict__ si,
                                             const int* __restrict__ sj,
                                             float* __restrict__ out,
                                             float* __restrict__ W) {
    const int tid = threadIdx.x, bid = blockIdx.x;
    const int lane = tid & 63, wave = tid >> 6;
    __shared__ float  sflat[256];
    __shared__ float  sinv8[8];
    __shared__ float  sM2[64];
    __shared__ double sd[256];
    __shared__ int    sLast;

    {   // colsum reduce: 32 groups of 8
        int k = tid & 7, g = tid >> 3;
        float s = 0.f;
        for (int b = g; b < NB; b += 32) s += W[CS_PART_OFF + b * 8 + k];
        sflat[tid] = s;
    }
    __syncthreads();
    if (tid < 8) {
        float s = 0.f;
        #pragma unroll
        for (int g = 0; g < 32; ++g) s += sflat[g * 8 + tid];
        sinv8[tid] = 1.f / s;
    }
    __syncthreads();
    if (tid < 64) {
        float m = 0.f;
        #pragma unroll
        for (int b = 0; b < 8; ++b) m += W[M2P_OFF + b * 64 + tid];
        sM2[tid] = m * sinv8[tid & 7];      // M2[k][j] = raw[k][j]/colsum[j]
    }
    __syncthreads();

    const float spa = W[SPA_OFF];

    // ---- pair: 4 rows per block, Ms rows computed on the fly ----
    float mr[4][8]; float bsv[4];
    const int srow0 = bid * 4;
    #pragma unroll
    for (int r = 0; r < 4; ++r) {
        float4 z0 = *(const float4*)&W[ZS_OFF + (size_t)(srow0 + r) * 8];
        float4 z1 = *(const float4*)&W[ZS_OFF + (size_t)(srow0 + r) * 8 + 4];
        float z[8] = {z0.x,z0.y,z0.z,z0.w,z1.x,z1.y,z1.z,z1.w};
        #pragma unroll
        for (int k = 0; k < 8; ++k) {
            float acc = 0.f;
            #pragma unroll
            for (int j = 0; j < 8; ++j) acc += sM2[k * 8 + j] * z[j];
            mr[r][k] = acc;
        }
        bsv[r] = W[BS_OFF + srow0 + r];
    }
    float accp = 0.f;
    #pragma unroll
    for (int m = 0; m < 8; ++m) {
        int t = tid + 256 * m;
        float4 z0 = *(const float4*)&W[ZS_OFF + (size_t)t * 8];
        float4 z1 = *(const float4*)&W[ZS_OFF + (size_t)t * 8 + 4];
        float z[8] = {z0.x,z0.y,z0.z,z0.w,z1.x,z1.y,z1.z,z1.w};
        float av[8];
        #pragma unroll
        for (int k = 0; k < 8; ++k) {
            float acc = 0.f;
            #pragma unroll
            for (int j = 0; j < 8; ++j) acc += sM2[k * 8 + j] * z[j];
            av[k] = acc;
        }
        float bt = W[BS_OFF + t];
        #pragma unroll
        for (int r = 0; r < 4; ++r) {
            float d, ss;
            d = mr[r][0] - av[0] + 1e-6f; ss  = d * d;
            d = mr[r][1] - av[1] + 1e-6f; ss += d * d;
            d = mr[r][2] - av[2] + 1e-6f; ss += d * d;
            d = mr[r][3] - av[3] + 1e-6f; ss += d * d;
            d = mr[r][4] - av[4] + 1e-6f; ss += d * d;
            d = mr[r][5] - av[5] + 1e-6f; ss += d * d;
            d = mr[r][6] - av[6] + 1e-6f; ss += d * d;
            d = mr[r][7] - av[7] + 1e-6f; ss += d * d;
            float val = __expf(bsv[r] + bt - spa * sqrtf(ss));
            if (t != srow0 + r) accp += val;
        }
    }

    // ---- sparse: 1 edge/thread; di - dj = M2 @ (zt_i - zt_j) ----
    float accs;
    {
        int e = bid * 256 + tid;             // PB*256 == E exactly
        int i = si[e], j = sj[e];
        const float* zt = W + ZT_OFF;
        float4 i0 = *(const float4*)&zt[(size_t)i * 8];
        float4 i1 = *(const float4*)&zt[(size_t)i * 8 + 4];
        float4 j0 = *(const float4*)&zt[(size_t)j * 8];
        float4 j1 = *(const float4*)&zt[(size_t)j * 8 + 4];
        float dz[8] = {i0.x - j0.x, i0.y - j0.y, i0.z - j0.z, i0.w - j0.w,
                       i1.x - j1.x, i1.y - j1.y, i1.z - j1.z, i1.w - j1.w};
        float ss = 0.f;
        #pragma unroll
        for (int k = 0; k < 8; ++k) {
            float acc = 0.f;
            #pragma unroll
            for (int jj = 0; jj < 8; ++jj) acc += sM2[k * 8 + jj] * dz[jj];
            acc += 1e-6f;
            ss += acc * acc;
        }
        accs = beta[i] + beta[j] - spa * sqrtf(ss);
    }

    float part = accs - 0.5f * 7.38905609893065f * accp;   // e^2
    #pragma unroll
    for (int off = 32; off; off >>= 1) part += __shfl_down(part, off, 64);
    if (lane == 0) sflat[wave] = part;
    __syncthreads();
    if (tid == 0) W[PART_OFF + bid] = sflat[0] + sflat[1] + sflat[2] + sflat[3];

    // ---- last-block deterministic final reduce ----
    if (tid == 0) {
        __threadfence();
        unsigned old = atomicAdd(&((unsigned*)W)[CNT_OFF], 1u);
        sLast = (old == PB - 1);
    }
    __syncthreads();
    if (sLast) {
        __threadfence();
        double s = (double)W[PART_OFF + tid] + (double)W[PART_OFF + tid + 256];
        sd[tid] = s;
        __syncthreads();
        for (int k = 128; k > 0; k >>= 1) {
            if (tid < k) sd[tid] += sd[tid + k];
            __syncthreads();
        }
        if (tid == 0) out[0] = (float)sd[0];
    }
}

extern "C" void kernel_launch(void* const* d_in, const int* in_sizes, int n_in,
                              void* d_out, int out_size, void* d_ws, size_t ws_size,
                              hipStream_t stream) {
    const float* beta       = (const float*)d_in[0];
    const float* a          = (const float*)d_in[1];
    const float* Zp         = (const float*)d_in[2];
    const float* Gp         = (const float*)d_in[3];
    const int*   sample_idx = (const int*)d_in[4];
    const int*   sparse_i   = (const int*)d_in[5];
    const int*   sparse_j   = (const int*)d_in[6];
    float* out = (float*)d_out;
    float* W   = (float*)d_ws;

    k1<<<dim3(NB), dim3(256), 0, stream>>>(beta, a, Zp, Gp, sample_idx, W);
    k2<<<dim3(PB), dim3(256), 0, stream>>>(beta, sparse_i, sparse_j, out, W);
}